// Round 9
// baseline (5272.103 us; speedup 1.0000x reference)
//
#include <hip/hip_runtime.h>
#include <cstddef>

#define BDIM 32
#define LEN 32
#define DD 384
#define NCELLS 528

typedef _Float16 h16;
typedef __attribute__((ext_vector_type(8))) _Float16 v8h;
typedef __attribute__((ext_vector_type(4))) float v4f;

__device__ __forceinline__ int offf(int k) { return k * 32 - ((k * (k - 1)) >> 1); }
static inline int offh(int k) { return k * 32 - ((k * (k - 1)) >> 1); }

__device__ __forceinline__ float sigma_h_f(float x) {
  float s = 1.0f / (1.0f + __expf(-x));      // sigmoid
  float r = sqrtf(s);
  float e2 = __expf(2.0f * r);
  float th = 1.0f - 2.0f / (e2 + 1.0f);      // tanh(r), r in (0,1)
  return x * th;
}

__device__ __forceinline__ size_t rowbase(int r, int gLs, int gOff) {
  if (gLs == 0) return (size_t)r;
  int b = r / gLs;
  int p = r - b * gLs;
  return (size_t)b * NCELLS + gOff + p;
}

__device__ __forceinline__ void split16(float v, h16& h, h16& l) {
  h = (h16)v;
  l = (h16)(v - (float)h);
}

// ---------------------------------------------------------------------------
// pack3: pre-split ALL GEMM weight constants to f16 hi/lo (one-time), plus
// x -> split (leaf GEMM A). Also zeroes score arrays.
__global__ __launch_bounds__(256) void pack3_k(
    const float* __restrict__ w0, const float* __restrict__ w1,
    const float* __restrict__ bi, const float* __restrict__ ow1,
    const float* __restrict__ obi, const float* __restrict__ w2,
    const float* __restrict__ ow2, const float* __restrict__ ow0,
    const float* __restrict__ lw, const float* __restrict__ x,
    h16* __restrict__ WCth, h16* __restrict__ WCtl,
    h16* __restrict__ W2th, h16* __restrict__ W2tl,
    h16* __restrict__ OW2th, h16* __restrict__ OW2tl,
    h16* __restrict__ OW0th, h16* __restrict__ OW0tl,
    h16* __restrict__ LWth, h16* __restrict__ LWtl,
    h16* __restrict__ xh, h16* __restrict__ xl,
    float* __restrict__ isp, float* __restrict__ osp) {
  int i = blockIdx.x * 256 + threadIdx.x;
  if (i < 1920 * 384) {
    int n = i / 384, k = i - n * 384;
    int sel = n / 384, c = n - sel * 384;
    const float* src = sel == 0 ? w0 : sel == 1 ? w1 : sel == 2 ? bi
                       : sel == 3 ? ow1 : obi;
    float v = src[k * 384 + c];
    h16 h, l; split16(v, h, l);
    WCth[i] = h; WCtl[i] = l;
  }
  if (i < 384 * 384) {
    int n = i / 384, k = i - n * 384;
    h16 h, l;
    split16(w2[k * 384 + n], h, l);  W2th[i] = h;  W2tl[i] = l;
    split16(ow2[k * 384 + n], h, l); OW2th[i] = h; OW2tl[i] = l;
    split16(ow0[k * 384 + n], h, l); OW0th[i] = h; OW0tl[i] = l;
    split16(lw[k * 384 + n], h, l);  LWth[i] = h;  LWtl[i] = l;
  }
  if (i < 1024 * 384) {
    h16 h, l; split16(x[i], h, l);
    xh[i] = h; xl[i] = l;
  }
  if (i < BDIM * NCELLS) { isp[i] = 0.0f; osp[i] = 0.0f; }
}

// ---------------------------------------------------------------------------
// Split-f16 MFMA GEMM, C-scatter mode (round-2 core, known-good).
__global__ __launch_bounds__(256) void gemmh(
    const h16* __restrict__ Ahp, const h16* __restrict__ Alp,
    const h16* __restrict__ Bth, const h16* __restrict__ Btl,
    const float* __restrict__ bias, float* __restrict__ C,
    int M, int N, int act, int gLs, int gOff) {
  __shared__ h16 Ah[64][40], Al[64][40];
  __shared__ h16 Bh[128][40], Bl[128][40];
  int tid = threadIdx.x;
  int w = tid >> 6, lane = tid & 63;
  int m0 = blockIdx.x * 64, n0 = blockIdx.y * 128;
  int r = lane & 15, q = lane >> 4;

  v4f acc[4][2];
#pragma unroll
  for (int i = 0; i < 4; ++i)
#pragma unroll
    for (int j = 0; j < 2; ++j) acc[i][j] = (v4f){0.f, 0.f, 0.f, 0.f};

  int sar = tid >> 2;
  int sak = (tid & 3) << 3;
  const h16* Aph = nullptr;
  const h16* Apl = nullptr;
  if (m0 + sar < M) {
    size_t rb = (size_t)(m0 + sar) * DD;
    Aph = Ahp + rb + sak;
    Apl = Alp + rb + sak;
  }
  int sbc = tid >> 1;
  int sbk = (tid & 1) << 4;
  const h16* Bph = Bth + (size_t)(n0 + sbc) * DD + sbk;
  const h16* Bpl = Btl + (size_t)(n0 + sbc) * DD + sbk;

  for (int k0 = 0; k0 < DD; k0 += 32) {
    v8h a_h = (v8h){0.f, 0.f, 0.f, 0.f, 0.f, 0.f, 0.f, 0.f};
    v8h a_l = a_h;
    if (Aph) {
      a_h = *reinterpret_cast<const v8h*>(Aph + k0);
      a_l = *reinterpret_cast<const v8h*>(Apl + k0);
    }
    v8h b_h0 = *reinterpret_cast<const v8h*>(Bph + k0);
    v8h b_h1 = *reinterpret_cast<const v8h*>(Bph + k0 + 8);
    v8h b_l0 = *reinterpret_cast<const v8h*>(Bpl + k0);
    v8h b_l1 = *reinterpret_cast<const v8h*>(Bpl + k0 + 8);
    __syncthreads();
    *reinterpret_cast<v8h*>(&Ah[sar][sak]) = a_h;
    *reinterpret_cast<v8h*>(&Al[sar][sak]) = a_l;
    *reinterpret_cast<v8h*>(&Bh[sbc][sbk]) = b_h0;
    *reinterpret_cast<v8h*>(&Bh[sbc][sbk + 8]) = b_h1;
    *reinterpret_cast<v8h*>(&Bl[sbc][sbk]) = b_l0;
    *reinterpret_cast<v8h*>(&Bl[sbc][sbk + 8]) = b_l1;
    __syncthreads();
    v8h afh[4], afl[4], bfh[2], bfl[2];
#pragma unroll
    for (int i = 0; i < 4; ++i) {
      afh[i] = *reinterpret_cast<const v8h*>(&Ah[i * 16 + r][q * 8]);
      afl[i] = *reinterpret_cast<const v8h*>(&Al[i * 16 + r][q * 8]);
    }
#pragma unroll
    for (int j = 0; j < 2; ++j) {
      bfh[j] = *reinterpret_cast<const v8h*>(&Bh[w * 32 + j * 16 + r][q * 8]);
      bfl[j] = *reinterpret_cast<const v8h*>(&Bl[w * 32 + j * 16 + r][q * 8]);
    }
#pragma unroll
    for (int i = 0; i < 4; ++i)
#pragma unroll
      for (int j = 0; j < 2; ++j) {
        acc[i][j] = __builtin_amdgcn_mfma_f32_16x16x32_f16(afl[i], bfh[j], acc[i][j], 0, 0, 0);
        acc[i][j] = __builtin_amdgcn_mfma_f32_16x16x32_f16(afh[i], bfl[j], acc[i][j], 0, 0, 0);
        acc[i][j] = __builtin_amdgcn_mfma_f32_16x16x32_f16(afh[i], bfh[j], acc[i][j], 0, 0, 0);
      }
  }

#pragma unroll
  for (int i = 0; i < 4; ++i) {
#pragma unroll
    for (int reg = 0; reg < 4; ++reg) {
      int rr = m0 + i * 16 + q * 4 + reg;
      if (rr >= M) continue;
      size_t cb = rowbase(rr, gLs, gOff) * (size_t)N;
#pragma unroll
      for (int j = 0; j < 2; ++j) {
        int col = n0 + w * 32 + j * 16 + r;
        float v = acc[i][j][reg];
        if (bias) v += bias[col];
        if (act) v = sigma_h_f(v);
        C[cb + col] = v;
      }
    }
  }
}

// ---------------------------------------------------------------------------
// gemmw: same GEMM core, but epilogue does the p-weighted per-cell reduction
// IN-BLOCK via LDS: hbar[c][col] += sum_n Pw[c*np+n]*sigma_h(acc+bias).
// Rows are grouped np per cell; a block's 64 rows cover 64/np(+1) cells.
// Exclusive cells -> plain store; straddling cells -> global atomicAdd onto
// pre-zeroed hbar. Eliminates the XC round-trip entirely.
__global__ __launch_bounds__(256) void gemmw(
    const h16* __restrict__ Ahp, const h16* __restrict__ Alp,
    const h16* __restrict__ Bth, const h16* __restrict__ Btl,
    const float* __restrict__ bias, const float* __restrict__ Pw,
    float* __restrict__ hbar, int M, int np) {
  __shared__ __align__(16) char pool[33280];
  h16 (*Ah)[40] = reinterpret_cast<h16(*)[40]>(pool);
  h16 (*Al)[40] = reinterpret_cast<h16(*)[40]>(pool + 5120);
  h16 (*Bh)[40] = reinterpret_cast<h16(*)[40]>(pool + 10240);
  h16 (*Bl)[40] = reinterpret_cast<h16(*)[40]>(pool + 20480);
  float (*hs)[128] = reinterpret_cast<float(*)[128]>(pool);

  int tid = threadIdx.x;
  int w = tid >> 6, lane = tid & 63;
  int m0 = blockIdx.x * 64, n0 = blockIdx.y * 128;
  int r = lane & 15, q = lane >> 4;

  v4f acc[4][2];
#pragma unroll
  for (int i = 0; i < 4; ++i)
#pragma unroll
    for (int j = 0; j < 2; ++j) acc[i][j] = (v4f){0.f, 0.f, 0.f, 0.f};

  int sar = tid >> 2;
  int sak = (tid & 3) << 3;
  const h16* Aph = nullptr;
  const h16* Apl = nullptr;
  if (m0 + sar < M) {
    size_t rb = (size_t)(m0 + sar) * DD;
    Aph = Ahp + rb + sak;
    Apl = Alp + rb + sak;
  }
  int sbc = tid >> 1;
  int sbk = (tid & 1) << 4;
  const h16* Bph = Bth + (size_t)(n0 + sbc) * DD + sbk;
  const h16* Bpl = Btl + (size_t)(n0 + sbc) * DD + sbk;

  for (int k0 = 0; k0 < DD; k0 += 32) {
    v8h a_h = (v8h){0.f, 0.f, 0.f, 0.f, 0.f, 0.f, 0.f, 0.f};
    v8h a_l = a_h;
    if (Aph) {
      a_h = *reinterpret_cast<const v8h*>(Aph + k0);
      a_l = *reinterpret_cast<const v8h*>(Apl + k0);
    }
    v8h b_h0 = *reinterpret_cast<const v8h*>(Bph + k0);
    v8h b_h1 = *reinterpret_cast<const v8h*>(Bph + k0 + 8);
    v8h b_l0 = *reinterpret_cast<const v8h*>(Bpl + k0);
    v8h b_l1 = *reinterpret_cast<const v8h*>(Bpl + k0 + 8);
    __syncthreads();
    *reinterpret_cast<v8h*>(&Ah[sar][sak]) = a_h;
    *reinterpret_cast<v8h*>(&Al[sar][sak]) = a_l;
    *reinterpret_cast<v8h*>(&Bh[sbc][sbk]) = b_h0;
    *reinterpret_cast<v8h*>(&Bh[sbc][sbk + 8]) = b_h1;
    *reinterpret_cast<v8h*>(&Bl[sbc][sbk]) = b_l0;
    *reinterpret_cast<v8h*>(&Bl[sbc][sbk + 8]) = b_l1;
    __syncthreads();
    v8h afh[4], afl[4], bfh[2], bfl[2];
#pragma unroll
    for (int i = 0; i < 4; ++i) {
      afh[i] = *reinterpret_cast<const v8h*>(&Ah[i * 16 + r][q * 8]);
      afl[i] = *reinterpret_cast<const v8h*>(&Al[i * 16 + r][q * 8]);
    }
#pragma unroll
    for (int j = 0; j < 2; ++j) {
      bfh[j] = *reinterpret_cast<const v8h*>(&Bh[w * 32 + j * 16 + r][q * 8]);
      bfl[j] = *reinterpret_cast<const v8h*>(&Bl[w * 32 + j * 16 + r][q * 8]);
    }
#pragma unroll
    for (int i = 0; i < 4; ++i)
#pragma unroll
      for (int j = 0; j < 2; ++j) {
        acc[i][j] = __builtin_amdgcn_mfma_f32_16x16x32_f16(afl[i], bfh[j], acc[i][j], 0, 0, 0);
        acc[i][j] = __builtin_amdgcn_mfma_f32_16x16x32_f16(afh[i], bfl[j], acc[i][j], 0, 0, 0);
        acc[i][j] = __builtin_amdgcn_mfma_f32_16x16x32_f16(afh[i], bfh[j], acc[i][j], 0, 0, 0);
      }
  }

  // ---- epilogue: LDS-staged p-weighted per-cell reduction ----
  __syncthreads();                   // staging LDS dead; reuse as hs
  int c0 = m0 / np;
  int mtop = m0 + 63 < M - 1 ? m0 + 63 : M - 1;
  int ncell = mtop / np - c0 + 1;    // <= 64
  for (int idx = tid; idx < ncell * 128; idx += 256)
    hs[idx >> 7][idx & 127] = 0.0f;
  __syncthreads();
#pragma unroll
  for (int i = 0; i < 4; ++i) {
#pragma unroll
    for (int reg = 0; reg < 4; ++reg) {
      int row = m0 + i * 16 + q * 4 + reg;
      if (row >= M) continue;
      int cl = row / np - c0;
      float pw = Pw ? Pw[row] : 1.0f;
#pragma unroll
      for (int j = 0; j < 2; ++j) {
        int col_l = w * 32 + j * 16 + r;
        float v = sigma_h_f(acc[i][j][reg] + bias[n0 + col_l]);
        atomicAdd(&hs[cl][col_l], pw * v);
      }
    }
  }
  __syncthreads();
  for (int idx = tid; idx < ncell * 128; idx += 256) {
    int cl = idx >> 7, col_l = idx & 127;
    int c = c0 + cl;
    float v = hs[cl][col_l];
    float* dst = &hbar[(size_t)c * DD + n0 + col_l];
    bool excl = (c * np >= m0) && ((c + 1) * np <= m0 + 64);
    if (excl) *dst = v;
    else atomicAdd(dst, v);
  }
}

// ---------------------------------------------------------------------------
// K1 inside: zero hbar row; scores+softmax+sbar -> is_; H rows split-f16,
// wave-parallel (each wave owns pairs n = wv, wv+4, ...).
__global__ __launch_bounds__(256) void k1_in(
    const float* __restrict__ PC, const float* __restrict__ ihp,
    float* __restrict__ isp, h16* __restrict__ Hh, h16* __restrict__ Hl,
    float* __restrict__ Pw, const float* __restrict__ B0,
    float* __restrict__ hbar, int L, int Ls, int offL) {
  int g = blockIdx.x;
  int b = g / Ls, pos = g - b * Ls;
  int tid = threadIdx.x, lane = tid & 63, wv = tid >> 6;
  __shared__ float scs[32];
  __shared__ float b0s[384];
  size_t cb = (size_t)b * NCELLS;
  for (int k = tid; k < 384; k += 256) {
    b0s[k] = B0[k];
    hbar[(size_t)g * DD + k] = 0.0f;
  }
  __syncthreads();
  for (int n = wv; n < L; n += 4) {
    int lc = offf(n) + pos;
    int rc = offf(L - 1 - n) + pos + n + 1;
    const float* u = PC + (cb + lc) * 1920 + 768;   // Uin[l]
    const float* v = ihp + (cb + rc) * (size_t)DD;  // ih[r]
    float s = 0.0f;
#pragma unroll
    for (int jj = 0; jj < 6; ++jj) s += u[lane + 64 * jj] * v[lane + 64 * jj];
#pragma unroll
    for (int o = 32; o; o >>= 1) s += __shfl_xor(s, o, 64);
    if (lane == 0) scs[n] = s + isp[cb + lc] + isp[cb + rc];
    const float* A0r = PC + (cb + lc) * 1920;
    const float* A1r = PC + (cb + rc) * 1920 + 384;
    size_t hb = ((size_t)g * L + n) * DD;
#pragma unroll
    for (int jj = 0; jj < 6; ++jj) {
      int k = lane + 64 * jj;
      float hv = sigma_h_f(A0r[k] + A1r[k] + b0s[k]);
      h16 h = (h16)hv;
      Hh[hb + k] = h;
      Hl[hb + k] = (h16)(hv - (float)h);
    }
  }
  __syncthreads();
  if (wv == 0) {
    float v = (lane < L) ? scs[lane] : -3.0e38f;
    float m = v;
#pragma unroll
    for (int o = 32; o; o >>= 1) m = fmaxf(m, __shfl_xor(m, o, 64));
    float e = (lane < L) ? __expf(v - m) : 0.0f;
    float S = e;
#pragma unroll
    for (int o = 32; o; o >>= 1) S += __shfl_xor(S, o, 64);
    float pn = e / S;
    if (lane < L) Pw[(size_t)g * L + lane] = pn;
    float sb = (lane < L) ? pn * v : 0.0f;
#pragma unroll
    for (int o = 32; o; o >>= 1) sb += __shfl_xor(sb, o, 64);
    if (lane == 0) isp[cb + offL + pos] = sb;
  }
}

// K1 outside (same structure).
__global__ __launch_bounds__(256) void k1_out(
    const float* __restrict__ PC, const float* __restrict__ P0,
    const float* __restrict__ ohp, const float* __restrict__ isp,
    float* __restrict__ osp, h16* __restrict__ Hh, h16* __restrict__ Hl,
    float* __restrict__ Pw, const float* __restrict__ B0,
    float* __restrict__ hbar, int L, int Ls, int Nc, int offL) {
  int g = blockIdx.x;
  int b = g / Ls, pos = g - b * Ls;
  int tid = threadIdx.x, lane = tid & 63, wv = tid >> 6;
  __shared__ float scs[32];
  __shared__ float b0s[384];
  size_t cb = (size_t)b * NCELLS;
  int cnt0 = 31 - pos - L;
  for (int k = tid; k < 384; k += 256) {
    b0s[k] = B0[k];
    hbar[(size_t)g * DD + k] = 0.0f;
  }
  __syncthreads();
  for (int j = wv; j < Nc; j += 4) {
    int par, sib;
    if (j < cnt0) { par = offf(L + j + 1) + pos; sib = offf(j) + pos + L + 1; }
    else { int s2 = j - cnt0; par = offf(L + s2 + 1) + pos - s2 - 1; sib = offf(s2) + pos - s2 - 1; }
    const float* u = PC + (cb + sib) * 1920 + 1536;  // Uout[sib]
    const float* v = ohp + (cb + par) * (size_t)DD;  // oh[par]
    float s = 0.0f;
#pragma unroll
    for (int jj = 0; jj < 6; ++jj) s += u[lane + 64 * jj] * v[lane + 64 * jj];
#pragma unroll
    for (int o = 32; o; o >>= 1) s += __shfl_xor(s, o, 64);
    if (lane == 0) scs[j] = s + isp[cb + sib] + osp[cb + par];
    const float* p0r = P0 + (cb + par) * (size_t)DD;
    const float* s1r = PC + (cb + sib) * 1920 + 1152;
    size_t hb = ((size_t)g * Nc + j) * DD;
#pragma unroll
    for (int jj = 0; jj < 6; ++jj) {
      int k = lane + 64 * jj;
      float hv = sigma_h_f(p0r[k] + s1r[k] + b0s[k]);
      h16 h = (h16)hv;
      Hh[hb + k] = h;
      Hl[hb + k] = (h16)(hv - (float)h);
    }
  }
  __syncthreads();
  if (wv == 0) {
    float v = (lane < Nc) ? scs[lane] : -3.0e38f;
    float m = v;
#pragma unroll
    for (int o = 32; o; o >>= 1) m = fmaxf(m, __shfl_xor(m, o, 64));
    float e = (lane < Nc) ? __expf(v - m) : 0.0f;
    float S = e;
#pragma unroll
    for (int o = 32; o; o >>= 1) S += __shfl_xor(S, o, 64);
    float pn = e / S;
    if (lane < Nc) Pw[(size_t)g * Nc + lane] = pn;
    float sb = (lane < Nc) ? pn * v : 0.0f;
#pragma unroll
    for (int o = 32; o; o >>= 1) sb += __shfl_xor(sb, o, 64);
    if (lane == 0) osp[cb + offL + pos] = sb;
  }
}

// ---------------------------------------------------------------------------
// K3: LN(hbar[g]) -> outArr cell (f32) + compact split f16 at row g.
__global__ __launch_bounds__(128) void k3_ln(
    const float* __restrict__ hbar,
    const float* __restrict__ lng, const float* __restrict__ lnb,
    float* __restrict__ outArr, h16* __restrict__ outh, h16* __restrict__ outl,
    int Ls, int offL) {
  int g = blockIdx.x;
  int b = g / Ls, pos = g - b * Ls;
  int tid = threadIdx.x;
  const float* hrow = hbar + (size_t)g * DD;
  float a0 = hrow[tid], a1 = hrow[tid + 128], a2 = hrow[tid + 256];
  int lane = tid & 63, wv = tid >> 6;
  float s = a0 + a1 + a2;
#pragma unroll
  for (int o = 32; o; o >>= 1) s += __shfl_xor(s, o, 64);
  __shared__ float r1[2], r2[2];
  if (lane == 0) r1[wv] = s;
  __syncthreads();
  float mean = (r1[0] + r1[1]) * (1.0f / 384.0f);
  float d0 = a0 - mean, d1 = a1 - mean, d2 = a2 - mean;
  float q = d0 * d0 + d1 * d1 + d2 * d2;
#pragma unroll
  for (int o = 32; o; o >>= 1) q += __shfl_xor(q, o, 64);
  if (lane == 0) r2[wv] = q;
  __syncthreads();
  float var = (r2[0] + r2[1]) * (1.0f / 384.0f);
  float inv = rsqrtf(var + 1e-5f);
  size_t ob = ((size_t)b * NCELLS + offL + pos) * DD;
  float* out = outArr + ob;
  float v0 = d0 * inv * lng[tid]       + lnb[tid];
  float v1 = d1 * inv * lng[tid + 128] + lnb[tid + 128];
  float v2 = d2 * inv * lng[tid + 256] + lnb[tid + 256];
  out[tid]       = v0;
  out[tid + 128] = v1;
  out[tid + 256] = v2;
  size_t sb = (size_t)g * DD;
  h16 h;
  h = (h16)v0; outh[sb + tid]       = h; outl[sb + tid]       = (h16)(v0 - (float)h);
  h = (h16)v1; outh[sb + tid + 128] = h; outl[sb + tid + 128] = (h16)(v1 - (float)h);
  h = (h16)v2; outh[sb + tid + 256] = h; outl[sb + tid + 256] = (h16)(v2 - (float)h);
}

// ---------------------------------------------------------------------------
// Root: oh[b][527] = LN(root_h), P0[b][527] = LN(root_h) @ out_W0.
__global__ __launch_bounds__(384) void root_k(
    const float* __restrict__ rooth, const float* __restrict__ lng,
    const float* __restrict__ lnb, const float* __restrict__ W0,
    float* __restrict__ ohp, float* __restrict__ P0) {
  int tid = threadIdx.x;
  int lane = tid & 63, wv = tid >> 6;
  __shared__ float rl[384];
  __shared__ float r1[6], r2[6];
  float x = rooth[tid];
  float s = x;
#pragma unroll
  for (int o = 32; o; o >>= 1) s += __shfl_xor(s, o, 64);
  if (lane == 0) r1[wv] = s;
  __syncthreads();
  float mean = (r1[0] + r1[1] + r1[2] + r1[3] + r1[4] + r1[5]) * (1.0f / 384.0f);
  float d = x - mean;
  float q = d * d;
#pragma unroll
  for (int o = 32; o; o >>= 1) q += __shfl_xor(q, o, 64);
  if (lane == 0) r2[wv] = q;
  __syncthreads();
  float var = (r2[0] + r2[1] + r2[2] + r2[3] + r2[4] + r2[5]) * (1.0f / 384.0f);
  float inv = rsqrtf(var + 1e-5f);
  float v = d * inv * lng[tid] + lnb[tid];
  rl[tid] = v;
  __syncthreads();
  for (int b2 = 0; b2 < BDIM; ++b2)
    ohp[((size_t)b2 * NCELLS + 527) * DD + tid] = v;
  float acc = 0.0f;
  for (int d2 = 0; d2 < 384; ++d2) acc += rl[d2] * W0[(size_t)d2 * 384 + tid];
  for (int b2 = 0; b2 < BDIM; ++b2)
    P0[((size_t)b2 * NCELLS + 527) * DD + tid] = acc;
}

// ---------------------------------------------------------------------------
extern "C" void kernel_launch(void* const* d_in, const int* in_sizes, int n_in,
                              void* d_out, int out_size, void* d_ws, size_t ws_size,
                              hipStream_t stream) {
  const float* x        = (const float*)d_in[0];
  const float* leaf_W   = (const float*)d_in[1];
  const float* leaf_b   = (const float*)d_in[2];
  const float* in_ln_g  = (const float*)d_in[3];
  const float* in_ln_b  = (const float*)d_in[4];
  const float* out_ln_g = (const float*)d_in[5];
  const float* out_ln_b = (const float*)d_in[6];
  const float* root_h   = (const float*)d_in[7];
  const float* in_bi    = (const float*)d_in[8];
  const float* out_bi   = (const float*)d_in[9];
  const float* in_W0    = (const float*)d_in[10];
  const float* in_W1    = (const float*)d_in[11];
  const float* in_B0    = (const float*)d_in[12];
  const float* in_W2    = (const float*)d_in[13];
  const float* in_B1    = (const float*)d_in[14];
  const float* out_W0   = (const float*)d_in[15];
  const float* out_W1   = (const float*)d_in[16];
  const float* out_B0   = (const float*)d_in[17];
  const float* out_W2   = (const float*)d_in[18];
  const float* out_B1   = (const float*)d_in[19];

  float* ih  = (float*)d_out;
  float* isp = ih + (size_t)BDIM * NCELLS * DD;
  float* oh  = isp + (size_t)BDIM * NCELLS;
  float* osp = oh + (size_t)BDIM * NCELLS * DD;

  // workspace layout — identical footprint to the round-2/8 kernels.
  float* PC  = (float*)d_ws;                                // 32,440,320 f
  float* P0  = PC + (size_t)32440320;                       //  6,488,064 f
  float* XCb = P0 + (size_t)6488064;                        // 12,189,696 f
  float* Pw  = XCb + (size_t)12189696;                      //     31,744 f
  h16* Hh    = (h16*)(Pw + 31744);                          // 12,189,696 h
  h16* Hl    = Hh + (size_t)12189696;                       // 12,189,696 h
  h16* WCth  = Hl + (size_t)12189696;                       //    737,280 h
  h16* WCtl  = WCth + (size_t)737280;
  h16* W2th  = WCtl + (size_t)737280;                       //    147,456 h each
  h16* W2tl  = W2th + (size_t)147456;
  h16* OW2th = W2tl + (size_t)147456;
  h16* OW2tl = OW2th + (size_t)147456;
  h16* OW0th = OW2tl + (size_t)147456;
  h16* OW0tl = OW0th + (size_t)147456;
  h16* LWth  = OW0tl + (size_t)147456;
  h16* LWtl  = LWth + (size_t)147456;
  // aliases:
  h16* xh = Hh;                          // rows 0..1023: split x (leaf only)
  h16* xl = Hl;
  h16* Ch = Hh + (size_t)16384 * DD;     // compact split of current level
  h16* Cl = Hl + (size_t)16384 * DD;
  float* hbar = XCb;                     // compact G x 384 accumulation

  pack3_k<<<2880, 256, 0, stream>>>(in_W0, in_W1, in_bi, out_W1, out_bi,
                                    in_W2, out_W2, out_W0, leaf_W, x,
                                    WCth, WCtl, W2th, W2tl, OW2th, OW2tl,
                                    OW0th, OW0tl, LWth, LWtl, xh, xl,
                                    isp, osp);

  // leaf: hbar = sigma_h(x @ leaf_W + b) (np=1, exclusive stores);
  // ih[level0] = LN(hbar); PC for leaves.
  gemmw<<<dim3(16, 3), 256, 0, stream>>>(xh, xl, LWth, LWtl, leaf_b, nullptr,
                                         hbar, 1024, 1);
  k3_ln<<<1024, 128, 0, stream>>>(hbar, in_ln_g, in_ln_b, ih, Ch, Cl, 32, 0);
  gemmh<<<dim3(16, 15), 256, 0, stream>>>(Ch, Cl, WCth, WCtl, nullptr, PC, 1024, 1920, 0, 32, 0);

  // inside pass
  for (int L = 1; L < LEN; ++L) {
    int Ls = LEN - L, G = BDIM * Ls, M = G * L, off = offh(L);
    k1_in<<<G, 256, 0, stream>>>(PC, ih, isp, Hh, Hl, Pw, in_B0, hbar, L, Ls, off);
    gemmw<<<dim3((M + 63) / 64, 3), 256, 0, stream>>>(Hh, Hl, W2th, W2tl, in_B1,
                                                      Pw, hbar, M, L);
    k3_ln<<<G, 128, 0, stream>>>(hbar, in_ln_g, in_ln_b, ih, Ch, Cl, Ls, off);
    gemmh<<<dim3((G + 63) / 64, 15), 256, 0, stream>>>(Ch, Cl, WCth, WCtl, nullptr, PC, G, 1920, 0, Ls, off);
  }

  // root
  root_k<<<1, 384, 0, stream>>>(root_h, out_ln_g, out_ln_b, out_W0, oh, P0);

  // outside pass
  for (int L = LEN - 2; L >= 0; --L) {
    int Ls = LEN - L, G = BDIM * Ls, Nc = LEN - 1 - L, M = G * Nc, off = offh(L);
    k1_out<<<G, 256, 0, stream>>>(PC, P0, oh, isp, osp, Hh, Hl, Pw, out_B0, hbar, L, Ls, Nc, off);
    gemmw<<<dim3((M + 63) / 64, 3), 256, 0, stream>>>(Hh, Hl, OW2th, OW2tl, out_B1,
                                                      Pw, hbar, M, Nc);
    k3_ln<<<G, 128, 0, stream>>>(hbar, out_ln_g, out_ln_b, oh, Ch, Cl, Ls, off);
    if (L > 0)
      gemmh<<<dim3((G + 63) / 64, 3), 256, 0, stream>>>(Ch, Cl, OW0th, OW0tl, nullptr, P0, G, 384, 0, Ls, off);
  }
}

// Round 10
// 4850.928 us; speedup vs baseline: 1.0868x; 1.0868x over previous
//
#include <hip/hip_runtime.h>
#include <cstddef>

#define BDIM 32
#define LEN 32
#define DD 384
#define NCELLS 528

typedef _Float16 h16;
typedef __attribute__((ext_vector_type(8))) _Float16 v8h;
typedef __attribute__((ext_vector_type(4))) float v4f;

__device__ __forceinline__ int offf(int k) { return k * 32 - ((k * (k - 1)) >> 1); }
static inline int offh(int k) { return k * 32 - ((k * (k - 1)) >> 1); }

__device__ __forceinline__ float sigma_h_f(float x) {
  float s = 1.0f / (1.0f + __expf(-x));      // sigmoid
  float r = sqrtf(s);
  float e2 = __expf(2.0f * r);
  float th = 1.0f - 2.0f / (e2 + 1.0f);      // tanh(r), r in (0,1)
  return x * th;
}

__device__ __forceinline__ size_t rowbase(int r, int gLs, int gOff) {
  if (gLs == 0) return (size_t)r;
  int b = r / gLs;
  int p = r - b * gLs;
  return (size_t)b * NCELLS + gOff + p;
}

__device__ __forceinline__ void split16(float v, h16& h, h16& l) {
  h = (h16)v;
  l = (h16)(v - (float)h);
}

// ---------------------------------------------------------------------------
// pack3: pre-split ALL GEMM weight constants to f16 hi/lo (one-time), plus
// x -> split (leaf GEMM A). Also zeroes score arrays.
__global__ __launch_bounds__(256) void pack3_k(
    const float* __restrict__ w0, const float* __restrict__ w1,
    const float* __restrict__ bi, const float* __restrict__ ow1,
    const float* __restrict__ obi, const float* __restrict__ w2,
    const float* __restrict__ ow2, const float* __restrict__ ow0,
    const float* __restrict__ lw, const float* __restrict__ x,
    h16* __restrict__ WCth, h16* __restrict__ WCtl,
    h16* __restrict__ W2th, h16* __restrict__ W2tl,
    h16* __restrict__ OW2th, h16* __restrict__ OW2tl,
    h16* __restrict__ OW0th, h16* __restrict__ OW0tl,
    h16* __restrict__ LWth, h16* __restrict__ LWtl,
    h16* __restrict__ xh, h16* __restrict__ xl,
    float* __restrict__ isp, float* __restrict__ osp) {
  int i = blockIdx.x * 256 + threadIdx.x;
  if (i < 1920 * 384) {
    int n = i / 384, k = i - n * 384;
    int sel = n / 384, c = n - sel * 384;
    const float* src = sel == 0 ? w0 : sel == 1 ? w1 : sel == 2 ? bi
                       : sel == 3 ? ow1 : obi;
    float v = src[k * 384 + c];
    h16 h, l; split16(v, h, l);
    WCth[i] = h; WCtl[i] = l;
  }
  if (i < 384 * 384) {
    int n = i / 384, k = i - n * 384;
    h16 h, l;
    split16(w2[k * 384 + n], h, l);  W2th[i] = h;  W2tl[i] = l;
    split16(ow2[k * 384 + n], h, l); OW2th[i] = h; OW2tl[i] = l;
    split16(ow0[k * 384 + n], h, l); OW0th[i] = h; OW0tl[i] = l;
    split16(lw[k * 384 + n], h, l);  LWth[i] = h;  LWtl[i] = l;
  }
  if (i < 1024 * 384) {
    h16 h, l; split16(x[i], h, l);
    xh[i] = h; xl[i] = l;
  }
  if (i < BDIM * NCELLS) { isp[i] = 0.0f; osp[i] = 0.0f; }
}

// ---------------------------------------------------------------------------
// Split-f16 MFMA GEMM (round-2/8 core, known-good). One change vs round 8:
// bijective XCD-chunked block remap decoded ROW-major, so the nby col-chunk
// blocks of one 64-row A-tile run on the SAME XCD -> A-tile is fetched from
// HBM once per row-tile and re-read from that XCD's L2 (weights are small
// enough to replicate in every XCD's L2).
__global__ __launch_bounds__(256) void gemmh(
    const h16* __restrict__ Ahp, const h16* __restrict__ Alp,
    const h16* __restrict__ Bth, const h16* __restrict__ Btl,
    const float* __restrict__ bias, float* __restrict__ C,
    int M, int N, int act, int gLs, int gOff) {
  __shared__ h16 Ah[64][40], Al[64][40];
  __shared__ h16 Bh[128][40], Bl[128][40];
  int tid = threadIdx.x;
  int w = tid >> 6, lane = tid & 63;

  // row-chunked XCD remap (m204 bijective): physical lin%8 = XCD (round-
  // robin dispatch); give each XCD a CONTIGUOUS range of work ids w, and
  // decode w row-major so a row-tile's col-chunks stay on one XCD.
  int nbx = gridDim.x, nby = gridDim.y;
  int total = nbx * nby;
  int lin = blockIdx.y * nbx + blockIdx.x;
  int xcd = lin & 7, slot = lin >> 3;
  int qd = total >> 3, rd = total & 7;
  int wk = (xcd < rd ? xcd * (qd + 1) : rd * (qd + 1) + (xcd - rd) * qd) + slot;
  int bx = wk / nby;        // row-tile
  int by = wk - bx * nby;   // col-chunk
  int m0 = bx * 64, n0 = by * 128;
  int r = lane & 15, q = lane >> 4;

  v4f acc[4][2];
#pragma unroll
  for (int i = 0; i < 4; ++i)
#pragma unroll
    for (int j = 0; j < 2; ++j) acc[i][j] = (v4f){0.f, 0.f, 0.f, 0.f};

  int sar = tid >> 2;
  int sak = (tid & 3) << 3;
  const h16* Aph = nullptr;
  const h16* Apl = nullptr;
  if (m0 + sar < M) {
    size_t rb = (size_t)(m0 + sar) * DD;
    Aph = Ahp + rb + sak;
    Apl = Alp + rb + sak;
  }
  int sbc = tid >> 1;
  int sbk = (tid & 1) << 4;
  const h16* Bph = Bth + (size_t)(n0 + sbc) * DD + sbk;
  const h16* Bpl = Btl + (size_t)(n0 + sbc) * DD + sbk;

  for (int k0 = 0; k0 < DD; k0 += 32) {
    v8h a_h = (v8h){0.f, 0.f, 0.f, 0.f, 0.f, 0.f, 0.f, 0.f};
    v8h a_l = a_h;
    if (Aph) {
      a_h = *reinterpret_cast<const v8h*>(Aph + k0);
      a_l = *reinterpret_cast<const v8h*>(Apl + k0);
    }
    v8h b_h0 = *reinterpret_cast<const v8h*>(Bph + k0);
    v8h b_h1 = *reinterpret_cast<const v8h*>(Bph + k0 + 8);
    v8h b_l0 = *reinterpret_cast<const v8h*>(Bpl + k0);
    v8h b_l1 = *reinterpret_cast<const v8h*>(Bpl + k0 + 8);
    __syncthreads();
    *reinterpret_cast<v8h*>(&Ah[sar][sak]) = a_h;
    *reinterpret_cast<v8h*>(&Al[sar][sak]) = a_l;
    *reinterpret_cast<v8h*>(&Bh[sbc][sbk]) = b_h0;
    *reinterpret_cast<v8h*>(&Bh[sbc][sbk + 8]) = b_h1;
    *reinterpret_cast<v8h*>(&Bl[sbc][sbk]) = b_l0;
    *reinterpret_cast<v8h*>(&Bl[sbc][sbk + 8]) = b_l1;
    __syncthreads();
    v8h afh[4], afl[4], bfh[2], bfl[2];
#pragma unroll
    for (int i = 0; i < 4; ++i) {
      afh[i] = *reinterpret_cast<const v8h*>(&Ah[i * 16 + r][q * 8]);
      afl[i] = *reinterpret_cast<const v8h*>(&Al[i * 16 + r][q * 8]);
    }
#pragma unroll
    for (int j = 0; j < 2; ++j) {
      bfh[j] = *reinterpret_cast<const v8h*>(&Bh[w * 32 + j * 16 + r][q * 8]);
      bfl[j] = *reinterpret_cast<const v8h*>(&Bl[w * 32 + j * 16 + r][q * 8]);
    }
#pragma unroll
    for (int i = 0; i < 4; ++i)
#pragma unroll
      for (int j = 0; j < 2; ++j) {
        acc[i][j] = __builtin_amdgcn_mfma_f32_16x16x32_f16(afl[i], bfh[j], acc[i][j], 0, 0, 0);
        acc[i][j] = __builtin_amdgcn_mfma_f32_16x16x32_f16(afh[i], bfl[j], acc[i][j], 0, 0, 0);
        acc[i][j] = __builtin_amdgcn_mfma_f32_16x16x32_f16(afh[i], bfh[j], acc[i][j], 0, 0, 0);
      }
  }

#pragma unroll
  for (int i = 0; i < 4; ++i) {
#pragma unroll
    for (int reg = 0; reg < 4; ++reg) {
      int rr = m0 + i * 16 + q * 4 + reg;
      if (rr >= M) continue;
      size_t cb = rowbase(rr, gLs, gOff) * (size_t)N;
#pragma unroll
      for (int j = 0; j < 2; ++j) {
        int col = n0 + w * 32 + j * 16 + r;
        float v = acc[i][j][reg];
        if (bias) v += bias[col];
        if (act) v = sigma_h_f(v);
        C[cb + col] = v;
      }
    }
  }
}

// ---------------------------------------------------------------------------
// K1 inside: scores+softmax+sbar -> is_, H rows split-f16. Wave-parallel:
// each wave owns pairs n = wv, wv+4, ... and produces both the score dot and
// the full 384-wide H row (6 chunks of 64 lanes).
__global__ __launch_bounds__(256) void k1_in(
    const float* __restrict__ PC, const float* __restrict__ ihp,
    float* __restrict__ isp, h16* __restrict__ Hh, h16* __restrict__ Hl,
    float* __restrict__ Pw, const float* __restrict__ B0,
    int L, int Ls, int offL) {
  int g = blockIdx.x;
  int b = g / Ls, pos = g - b * Ls;
  int tid = threadIdx.x, lane = tid & 63, wv = tid >> 6;
  __shared__ float scs[32];
  __shared__ float b0s[384];
  size_t cb = (size_t)b * NCELLS;
  for (int k = tid; k < 384; k += 256) b0s[k] = B0[k];
  __syncthreads();
  for (int n = wv; n < L; n += 4) {
    int lc = offf(n) + pos;
    int rc = offf(L - 1 - n) + pos + n + 1;
    const float* u = PC + (cb + lc) * 1920 + 768;   // Uin[l]
    const float* v = ihp + (cb + rc) * (size_t)DD;  // ih[r]
    float s = 0.0f;
#pragma unroll
    for (int jj = 0; jj < 6; ++jj) s += u[lane + 64 * jj] * v[lane + 64 * jj];
#pragma unroll
    for (int o = 32; o; o >>= 1) s += __shfl_xor(s, o, 64);
    if (lane == 0) scs[n] = s + isp[cb + lc] + isp[cb + rc];
    // H row n (wave-parallel, overlapped with the score loads)
    const float* A0r = PC + (cb + lc) * 1920;
    const float* A1r = PC + (cb + rc) * 1920 + 384;
    size_t hb = ((size_t)g * L + n) * DD;
#pragma unroll
    for (int jj = 0; jj < 6; ++jj) {
      int k = lane + 64 * jj;
      float hv = sigma_h_f(A0r[k] + A1r[k] + b0s[k]);
      h16 h = (h16)hv;
      Hh[hb + k] = h;
      Hl[hb + k] = (h16)(hv - (float)h);
    }
  }
  __syncthreads();
  if (wv == 0) {
    float v = (lane < L) ? scs[lane] : -3.0e38f;
    float m = v;
#pragma unroll
    for (int o = 32; o; o >>= 1) m = fmaxf(m, __shfl_xor(m, o, 64));
    float e = (lane < L) ? __expf(v - m) : 0.0f;
    float S = e;
#pragma unroll
    for (int o = 32; o; o >>= 1) S += __shfl_xor(S, o, 64);
    float pn = e / S;
    if (lane < L) Pw[(size_t)g * L + lane] = pn;
    float sb = (lane < L) ? pn * v : 0.0f;
#pragma unroll
    for (int o = 32; o; o >>= 1) sb += __shfl_xor(sb, o, 64);
    if (lane == 0) isp[cb + offL + pos] = sb;
  }
}

// K1 outside (same wave-parallel fusion).
__global__ __launch_bounds__(256) void k1_out(
    const float* __restrict__ PC, const float* __restrict__ P0,
    const float* __restrict__ ohp, const float* __restrict__ isp,
    float* __restrict__ osp, h16* __restrict__ Hh, h16* __restrict__ Hl,
    float* __restrict__ Pw, const float* __restrict__ B0,
    int L, int Ls, int Nc, int offL) {
  int g = blockIdx.x;
  int b = g / Ls, pos = g - b * Ls;
  int tid = threadIdx.x, lane = tid & 63, wv = tid >> 6;
  __shared__ float scs[32];
  __shared__ float b0s[384];
  size_t cb = (size_t)b * NCELLS;
  int cnt0 = 31 - pos - L;
  for (int k = tid; k < 384; k += 256) b0s[k] = B0[k];
  __syncthreads();
  for (int j = wv; j < Nc; j += 4) {
    int par, sib;
    if (j < cnt0) { par = offf(L + j + 1) + pos; sib = offf(j) + pos + L + 1; }
    else { int s2 = j - cnt0; par = offf(L + s2 + 1) + pos - s2 - 1; sib = offf(s2) + pos - s2 - 1; }
    const float* u = PC + (cb + sib) * 1920 + 1536;  // Uout[sib]
    const float* v = ohp + (cb + par) * (size_t)DD;  // oh[par]
    float s = 0.0f;
#pragma unroll
    for (int jj = 0; jj < 6; ++jj) s += u[lane + 64 * jj] * v[lane + 64 * jj];
#pragma unroll
    for (int o = 32; o; o >>= 1) s += __shfl_xor(s, o, 64);
    if (lane == 0) scs[j] = s + isp[cb + sib] + osp[cb + par];
    // H row j (wave-parallel)
    const float* p0r = P0 + (cb + par) * (size_t)DD;
    const float* s1r = PC + (cb + sib) * 1920 + 1152;
    size_t hb = ((size_t)g * Nc + j) * DD;
#pragma unroll
    for (int jj = 0; jj < 6; ++jj) {
      int k = lane + 64 * jj;
      float hv = sigma_h_f(p0r[k] + s1r[k] + b0s[k]);
      h16 h = (h16)hv;
      Hh[hb + k] = h;
      Hl[hb + k] = (h16)(hv - (float)h);
    }
  }
  __syncthreads();
  if (wv == 0) {
    float v = (lane < Nc) ? scs[lane] : -3.0e38f;
    float m = v;
#pragma unroll
    for (int o = 32; o; o >>= 1) m = fmaxf(m, __shfl_xor(m, o, 64));
    float e = (lane < Nc) ? __expf(v - m) : 0.0f;
    float S = e;
#pragma unroll
    for (int o = 32; o; o >>= 1) S += __shfl_xor(S, o, 64);
    float pn = e / S;
    if (lane < Nc) Pw[(size_t)g * Nc + lane] = pn;
    float sb = (lane < Nc) ? pn * v : 0.0f;
#pragma unroll
    for (int o = 32; o; o >>= 1) sb += __shfl_xor(sb, o, 64);
    if (lane == 0) osp[cb + offL + pos] = sb;
  }
}

// ---------------------------------------------------------------------------
// K3: hbar = LN(sum_n p[n]*XC[row n]) -> outArr cell (f32) + COMPACT split
// f16 copy at row g (feeds the following GEMM's A operand).
__global__ __launch_bounds__(128) void k3_red_ln(
    const float* __restrict__ XC, const float* __restrict__ Pw,
    const float* __restrict__ lng, const float* __restrict__ lnb,
    float* __restrict__ outArr, h16* __restrict__ outh, h16* __restrict__ outl,
    int L, int Ls, int offL) {
  int g = blockIdx.x;
  int b = g / Ls, pos = g - b * Ls;
  int tid = threadIdx.x;
  float a0 = 0, a1 = 0, a2 = 0;
  const float* base = XC + (size_t)g * L * DD;
  for (int n = 0; n < L; ++n) {
    float pw = Pw ? Pw[(size_t)g * L + n] : 1.0f;
    const float* row = base + (size_t)n * DD;
    a0 += pw * row[tid];
    a1 += pw * row[tid + 128];
    a2 += pw * row[tid + 256];
  }
  int lane = tid & 63, wv = tid >> 6;
  float s = a0 + a1 + a2;
#pragma unroll
  for (int o = 32; o; o >>= 1) s += __shfl_xor(s, o, 64);
  __shared__ float r1[2], r2[2];
  if (lane == 0) r1[wv] = s;
  __syncthreads();
  float mean = (r1[0] + r1[1]) * (1.0f / 384.0f);
  float d0 = a0 - mean, d1 = a1 - mean, d2 = a2 - mean;
  float q = d0 * d0 + d1 * d1 + d2 * d2;
#pragma unroll
  for (int o = 32; o; o >>= 1) q += __shfl_xor(q, o, 64);
  if (lane == 0) r2[wv] = q;
  __syncthreads();
  float var = (r2[0] + r2[1]) * (1.0f / 384.0f);
  float inv = rsqrtf(var + 1e-5f);
  size_t ob = ((size_t)b * NCELLS + offL + pos) * DD;
  float* out = outArr + ob;
  float v0 = d0 * inv * lng[tid]       + lnb[tid];
  float v1 = d1 * inv * lng[tid + 128] + lnb[tid + 128];
  float v2 = d2 * inv * lng[tid + 256] + lnb[tid + 256];
  out[tid]       = v0;
  out[tid + 128] = v1;
  out[tid + 256] = v2;
  size_t sb = (size_t)g * DD;
  h16 h;
  h = (h16)v0; outh[sb + tid]       = h; outl[sb + tid]       = (h16)(v0 - (float)h);
  h = (h16)v1; outh[sb + tid + 128] = h; outl[sb + tid + 128] = (h16)(v1 - (float)h);
  h = (h16)v2; outh[sb + tid + 256] = h; outl[sb + tid + 256] = (h16)(v2 - (float)h);
}

// ---------------------------------------------------------------------------
// Root: oh[b][527] = LN(root_h), P0[b][527] = LN(root_h) @ out_W0.
__global__ __launch_bounds__(384) void root_k(
    const float* __restrict__ rooth, const float* __restrict__ lng,
    const float* __restrict__ lnb, const float* __restrict__ W0,
    float* __restrict__ ohp, float* __restrict__ P0) {
  int tid = threadIdx.x;
  int lane = tid & 63, wv = tid >> 6;
  __shared__ float rl[384];
  __shared__ float r1[6], r2[6];
  float x = rooth[tid];
  float s = x;
#pragma unroll
  for (int o = 32; o; o >>= 1) s += __shfl_xor(s, o, 64);
  if (lane == 0) r1[wv] = s;
  __syncthreads();
  float mean = (r1[0] + r1[1] + r1[2] + r1[3] + r1[4] + r1[5]) * (1.0f / 384.0f);
  float d = x - mean;
  float q = d * d;
#pragma unroll
  for (int o = 32; o; o >>= 1) q += __shfl_xor(q, o, 64);
  if (lane == 0) r2[wv] = q;
  __syncthreads();
  float var = (r2[0] + r2[1] + r2[2] + r2[3] + r2[4] + r2[5]) * (1.0f / 384.0f);
  float inv = rsqrtf(var + 1e-5f);
  float v = d * inv * lng[tid] + lnb[tid];
  rl[tid] = v;
  __syncthreads();
  for (int b2 = 0; b2 < BDIM; ++b2)
    ohp[((size_t)b2 * NCELLS + 527) * DD + tid] = v;
  float acc = 0.0f;
  for (int d2 = 0; d2 < 384; ++d2) acc += rl[d2] * W0[(size_t)d2 * 384 + tid];
  for (int b2 = 0; b2 < BDIM; ++b2)
    P0[((size_t)b2 * NCELLS + 527) * DD + tid] = acc;
}

// ---------------------------------------------------------------------------
extern "C" void kernel_launch(void* const* d_in, const int* in_sizes, int n_in,
                              void* d_out, int out_size, void* d_ws, size_t ws_size,
                              hipStream_t stream) {
  const float* x        = (const float*)d_in[0];
  const float* leaf_W   = (const float*)d_in[1];
  const float* leaf_b   = (const float*)d_in[2];
  const float* in_ln_g  = (const float*)d_in[3];
  const float* in_ln_b  = (const float*)d_in[4];
  const float* out_ln_g = (const float*)d_in[5];
  const float* out_ln_b = (const float*)d_in[6];
  const float* root_h   = (const float*)d_in[7];
  const float* in_bi    = (const float*)d_in[8];
  const float* out_bi   = (const float*)d_in[9];
  const float* in_W0    = (const float*)d_in[10];
  const float* in_W1    = (const float*)d_in[11];
  const float* in_B0    = (const float*)d_in[12];
  const float* in_W2    = (const float*)d_in[13];
  const float* in_B1    = (const float*)d_in[14];
  const float* out_W0   = (const float*)d_in[15];
  const float* out_W1   = (const float*)d_in[16];
  const float* out_B0   = (const float*)d_in[17];
  const float* out_W2   = (const float*)d_in[18];
  const float* out_B1   = (const float*)d_in[19];

  float* ih  = (float*)d_out;
  float* isp = ih + (size_t)BDIM * NCELLS * DD;
  float* oh  = isp + (size_t)BDIM * NCELLS;
  float* osp = oh + (size_t)BDIM * NCELLS * DD;

  // workspace layout — identical footprint to the round-2/8 kernels.
  float* PC  = (float*)d_ws;                                // 32,440,320 f
  float* P0  = PC + (size_t)32440320;                       //  6,488,064 f
  float* XCb = P0 + (size_t)6488064;                        // 12,189,696 f
  float* Pw  = XCb + (size_t)12189696;                      //     31,744 f
  h16* Hh    = (h16*)(Pw + 31744);                          // 12,189,696 h
  h16* Hl    = Hh + (size_t)12189696;                       // 12,189,696 h
  h16* WCth  = Hl + (size_t)12189696;                       //    737,280 h
  h16* WCtl  = WCth + (size_t)737280;
  h16* W2th  = WCtl + (size_t)737280;                       //    147,456 h each
  h16* W2tl  = W2th + (size_t)147456;
  h16* OW2th = W2tl + (size_t)147456;
  h16* OW2tl = OW2th + (size_t)147456;
  h16* OW0th = OW2tl + (size_t)147456;
  h16* OW0tl = OW0th + (size_t)147456;
  h16* LWth  = OW0tl + (size_t)147456;
  h16* LWtl  = LWth + (size_t)147456;
  // aliases inside the H buffer:
  h16* xh = Hh;                          // rows 0..1023: split x (leaf only)
  h16* xl = Hl;
  h16* Ch = Hh + (size_t)16384 * DD;     // compact split of current level
  h16* Cl = Hl + (size_t)16384 * DD;

  pack3_k<<<2880, 256, 0, stream>>>(in_W0, in_W1, in_bi, out_W1, out_bi,
                                    in_W2, out_W2, out_W0, leaf_W, x,
                                    WCth, WCtl, W2th, W2tl, OW2th, OW2tl,
                                    OW0th, OW0tl, LWth, LWtl, xh, xl,
                                    isp, osp);

  // leaf: T = sigma_h(x @ leaf_W + b); ih[level0] = LN(T); PC for leaves
  gemmh<<<dim3(16, 3), 256, 0, stream>>>(xh, xl, LWth, LWtl, leaf_b, XCb, 1024, 384, 1, 0, 0);
  k3_red_ln<<<1024, 128, 0, stream>>>(XCb, nullptr, in_ln_g, in_ln_b, ih, Ch, Cl, 1, 32, 0);
  gemmh<<<dim3(16, 15), 256, 0, stream>>>(Ch, Cl, WCth, WCtl, nullptr, PC, 1024, 1920, 0, 32, 0);

  // inside pass
  for (int L = 1; L < LEN; ++L) {
    int Ls = LEN - L, G = BDIM * Ls, M = G * L, off = offh(L);
    k1_in<<<G, 256, 0, stream>>>(PC, ih, isp, Hh, Hl, Pw, in_B0, L, Ls, off);
    gemmh<<<dim3((M + 63) / 64, 3), 256, 0, stream>>>(Hh, Hl, W2th, W2tl, in_B1, XCb, M, 384, 1, 0, 0);
    k3_red_ln<<<G, 128, 0, stream>>>(XCb, Pw, in_ln_g, in_ln_b, ih, Ch, Cl, L, Ls, off);
    gemmh<<<dim3((G + 63) / 64, 15), 256, 0, stream>>>(Ch, Cl, WCth, WCtl, nullptr, PC, G, 1920, 0, Ls, off);
  }

  // root
  root_k<<<1, 384, 0, stream>>>(root_h, out_ln_g, out_ln_b, out_W0, oh, P0);

  // outside pass
  for (int L = LEN - 2; L >= 0; --L) {
    int Ls = LEN - L, G = BDIM * Ls, Nc = LEN - 1 - L, M = G * Nc, off = offh(L);
    k1_out<<<G, 256, 0, stream>>>(PC, P0, oh, isp, osp, Hh, Hl, Pw, out_B0, L, Ls, Nc, off);
    gemmh<<<dim3((M + 63) / 64, 3), 256, 0, stream>>>(Hh, Hl, OW2th, OW2tl, out_B1, XCb, M, 384, 1, 0, 0);
    k3_red_ln<<<G, 128, 0, stream>>>(XCb, Pw, out_ln_g, out_ln_b, oh, Ch, Cl, Nc, Ls, off);
    if (L > 0)
      gemmh<<<dim3((G + 63) / 64, 3), 256, 0, stream>>>(Ch, Cl, OW0th, OW0tl, nullptr, P0, G, 384, 0, Ls, off);
  }
}

// Round 11
// 4135.262 us; speedup vs baseline: 1.2749x; 1.1731x over previous
//
#include <hip/hip_runtime.h>
#include <cstddef>

#define BDIM 32
#define LEN 32
#define DD 384
#define NCELLS 528

typedef _Float16 h16;
typedef __attribute__((ext_vector_type(8))) _Float16 v8h;
typedef __attribute__((ext_vector_type(4))) float v4f;

__device__ __forceinline__ int offf(int k) { return k * 32 - ((k * (k - 1)) >> 1); }
static inline int offh(int k) { return k * 32 - ((k * (k - 1)) >> 1); }

__device__ __forceinline__ float sigma_h_f(float x) {
  float s = 1.0f / (1.0f + __expf(-x));      // sigmoid
  float r = sqrtf(s);
  float e2 = __expf(2.0f * r);
  float th = 1.0f - 2.0f / (e2 + 1.0f);      // tanh(r), r in (0,1)
  return x * th;
}

__device__ __forceinline__ size_t rowbase(int r, int gLs, int gOff) {
  if (gLs == 0) return (size_t)r;
  int b = r / gLs;
  int p = r - b * gLs;
  return (size_t)b * NCELLS + gOff + p;
}

__device__ __forceinline__ void split16(float v, h16& h, h16& l) {
  h = (h16)v;
  l = (h16)(v - (float)h);
}

// ---------------------------------------------------------------------------
// pack3: pre-split ALL GEMM weight constants to f16 hi/lo (one-time), plus
// x -> split (leaf GEMM A). Also zeroes score arrays.
__global__ __launch_bounds__(256) void pack3_k(
    const float* __restrict__ w0, const float* __restrict__ w1,
    const float* __restrict__ bi, const float* __restrict__ ow1,
    const float* __restrict__ obi, const float* __restrict__ w2,
    const float* __restrict__ ow2, const float* __restrict__ ow0,
    const float* __restrict__ lw, const float* __restrict__ x,
    h16* __restrict__ WCth, h16* __restrict__ WCtl,
    h16* __restrict__ W2th, h16* __restrict__ W2tl,
    h16* __restrict__ OW2th, h16* __restrict__ OW2tl,
    h16* __restrict__ OW0th, h16* __restrict__ OW0tl,
    h16* __restrict__ LWth, h16* __restrict__ LWtl,
    h16* __restrict__ xh, h16* __restrict__ xl,
    float* __restrict__ isp, float* __restrict__ osp) {
  int i = blockIdx.x * 256 + threadIdx.x;
  if (i < 1920 * 384) {
    int n = i / 384, k = i - n * 384;
    int sel = n / 384, c = n - sel * 384;
    const float* src = sel == 0 ? w0 : sel == 1 ? w1 : sel == 2 ? bi
                       : sel == 3 ? ow1 : obi;
    float v = src[k * 384 + c];
    h16 h, l; split16(v, h, l);
    WCth[i] = h; WCtl[i] = l;
  }
  if (i < 384 * 384) {
    int n = i / 384, k = i - n * 384;
    h16 h, l;
    split16(w2[k * 384 + n], h, l);  W2th[i] = h;  W2tl[i] = l;
    split16(ow2[k * 384 + n], h, l); OW2th[i] = h; OW2tl[i] = l;
    split16(ow0[k * 384 + n], h, l); OW0th[i] = h; OW0tl[i] = l;
    split16(lw[k * 384 + n], h, l);  LWth[i] = h;  LWtl[i] = l;
  }
  if (i < 1024 * 384) {
    h16 h, l; split16(x[i], h, l);
    xh[i] = h; xl[i] = l;
  }
  if (i < BDIM * NCELLS) { isp[i] = 0.0f; osp[i] = 0.0f; }
}

// ---------------------------------------------------------------------------
// Split-f16 MFMA GEMM (round-10 version: core + row-chunked XCD remap).
__global__ __launch_bounds__(256) void gemmh(
    const h16* __restrict__ Ahp, const h16* __restrict__ Alp,
    const h16* __restrict__ Bth, const h16* __restrict__ Btl,
    const float* __restrict__ bias, float* __restrict__ C,
    int M, int N, int act, int gLs, int gOff) {
  __shared__ h16 Ah[64][40], Al[64][40];
  __shared__ h16 Bh[128][40], Bl[128][40];
  int tid = threadIdx.x;
  int w = tid >> 6, lane = tid & 63;

  int nbx = gridDim.x, nby = gridDim.y;
  int total = nbx * nby;
  int lin = blockIdx.y * nbx + blockIdx.x;
  int xcd = lin & 7, slot = lin >> 3;
  int qd = total >> 3, rd = total & 7;
  int wk = (xcd < rd ? xcd * (qd + 1) : rd * (qd + 1) + (xcd - rd) * qd) + slot;
  int bx = wk / nby;
  int by = wk - bx * nby;
  int m0 = bx * 64, n0 = by * 128;
  int r = lane & 15, q = lane >> 4;

  v4f acc[4][2];
#pragma unroll
  for (int i = 0; i < 4; ++i)
#pragma unroll
    for (int j = 0; j < 2; ++j) acc[i][j] = (v4f){0.f, 0.f, 0.f, 0.f};

  int sar = tid >> 2;
  int sak = (tid & 3) << 3;
  const h16* Aph = nullptr;
  const h16* Apl = nullptr;
  if (m0 + sar < M) {
    size_t rb = (size_t)(m0 + sar) * DD;
    Aph = Ahp + rb + sak;
    Apl = Alp + rb + sak;
  }
  int sbc = tid >> 1;
  int sbk = (tid & 1) << 4;
  const h16* Bph = Bth + (size_t)(n0 + sbc) * DD + sbk;
  const h16* Bpl = Btl + (size_t)(n0 + sbc) * DD + sbk;

  for (int k0 = 0; k0 < DD; k0 += 32) {
    v8h a_h = (v8h){0.f, 0.f, 0.f, 0.f, 0.f, 0.f, 0.f, 0.f};
    v8h a_l = a_h;
    if (Aph) {
      a_h = *reinterpret_cast<const v8h*>(Aph + k0);
      a_l = *reinterpret_cast<const v8h*>(Apl + k0);
    }
    v8h b_h0 = *reinterpret_cast<const v8h*>(Bph + k0);
    v8h b_h1 = *reinterpret_cast<const v8h*>(Bph + k0 + 8);
    v8h b_l0 = *reinterpret_cast<const v8h*>(Bpl + k0);
    v8h b_l1 = *reinterpret_cast<const v8h*>(Bpl + k0 + 8);
    __syncthreads();
    *reinterpret_cast<v8h*>(&Ah[sar][sak]) = a_h;
    *reinterpret_cast<v8h*>(&Al[sar][sak]) = a_l;
    *reinterpret_cast<v8h*>(&Bh[sbc][sbk]) = b_h0;
    *reinterpret_cast<v8h*>(&Bh[sbc][sbk + 8]) = b_h1;
    *reinterpret_cast<v8h*>(&Bl[sbc][sbk]) = b_l0;
    *reinterpret_cast<v8h*>(&Bl[sbc][sbk + 8]) = b_l1;
    __syncthreads();
    v8h afh[4], afl[4], bfh[2], bfl[2];
#pragma unroll
    for (int i = 0; i < 4; ++i) {
      afh[i] = *reinterpret_cast<const v8h*>(&Ah[i * 16 + r][q * 8]);
      afl[i] = *reinterpret_cast<const v8h*>(&Al[i * 16 + r][q * 8]);
    }
#pragma unroll
    for (int j = 0; j < 2; ++j) {
      bfh[j] = *reinterpret_cast<const v8h*>(&Bh[w * 32 + j * 16 + r][q * 8]);
      bfl[j] = *reinterpret_cast<const v8h*>(&Bl[w * 32 + j * 16 + r][q * 8]);
    }
#pragma unroll
    for (int i = 0; i < 4; ++i)
#pragma unroll
      for (int j = 0; j < 2; ++j) {
        acc[i][j] = __builtin_amdgcn_mfma_f32_16x16x32_f16(afl[i], bfh[j], acc[i][j], 0, 0, 0);
        acc[i][j] = __builtin_amdgcn_mfma_f32_16x16x32_f16(afh[i], bfl[j], acc[i][j], 0, 0, 0);
        acc[i][j] = __builtin_amdgcn_mfma_f32_16x16x32_f16(afh[i], bfh[j], acc[i][j], 0, 0, 0);
      }
  }

#pragma unroll
  for (int i = 0; i < 4; ++i) {
#pragma unroll
    for (int reg = 0; reg < 4; ++reg) {
      int rr = m0 + i * 16 + q * 4 + reg;
      if (rr >= M) continue;
      size_t cb = rowbase(rr, gLs, gOff) * (size_t)N;
#pragma unroll
      for (int j = 0; j < 2; ++j) {
        int col = n0 + w * 32 + j * 16 + r;
        float v = acc[i][j][reg];
        if (bias) v += bias[col];
        if (act) v = sigma_h_f(v);
        C[cb + col] = v;
      }
    }
  }
}

// ---------------------------------------------------------------------------
// k1s: PURE streaming pair kernel. grid = (G, ceil(np/4)), one WAVE per pair.
// Writes raw score dot (no softmax, no isp bias — k3 adds those) and the
// split-f16 H row. 4-8x more blocks than the old per-cell k1.
__global__ __launch_bounds__(256) void k1s(
    const float* __restrict__ PC, const float* __restrict__ P0,
    const float* __restrict__ vArr, float* __restrict__ scores,
    h16* __restrict__ Hh, h16* __restrict__ Hl,
    const float* __restrict__ B0, int lvl, int np, int Ls, int inside) {
  int g = blockIdx.x;
  int b = g / Ls, pos = g - b * Ls;
  int tid = threadIdx.x, lane = tid & 63, wv = tid >> 6;
  __shared__ float b0s[384];
  size_t cb = (size_t)b * NCELLS;
  for (int k = tid; k < 384; k += 256) b0s[k] = B0[k];
  __syncthreads();
  int n = blockIdx.y * 4 + wv;
  if (n >= np) return;

  const float *u, *v, *A0r, *A1r;
  if (inside) {
    int lc = offf(n) + pos;
    int rc = offf(np - 1 - n) + pos + n + 1;
    u   = PC + (cb + lc) * 1920 + 768;
    v   = vArr + (cb + rc) * (size_t)DD;
    A0r = PC + (cb + lc) * 1920;
    A1r = PC + (cb + rc) * 1920 + 384;
  } else {
    int par, sib;
    int cnt0 = 31 - pos - lvl;
    if (n < cnt0) { par = offf(lvl + n + 1) + pos; sib = offf(n) + pos + lvl + 1; }
    else { int s2 = n - cnt0; par = offf(lvl + s2 + 1) + pos - s2 - 1; sib = offf(s2) + pos - s2 - 1; }
    u   = PC + (cb + sib) * 1920 + 1536;
    v   = vArr + (cb + par) * (size_t)DD;
    A0r = P0 + (cb + par) * (size_t)DD;
    A1r = PC + (cb + sib) * 1920 + 1152;
  }
  float s = 0.0f;
#pragma unroll
  for (int jj = 0; jj < 6; ++jj) s += u[lane + 64 * jj] * v[lane + 64 * jj];
#pragma unroll
  for (int o = 32; o; o >>= 1) s += __shfl_xor(s, o, 64);
  if (lane == 0) scores[(size_t)g * np + n] = s;
  size_t hb = ((size_t)g * np + n) * DD;
#pragma unroll
  for (int jj = 0; jj < 6; ++jj) {
    int k = lane + 64 * jj;
    float hv = sigma_h_f(A0r[k] + A1r[k] + b0s[k]);
    h16 h = (h16)hv;
    Hh[hb + k] = h;
    Hl[hb + k] = (h16)(hv - (float)h);
  }
}

// ---------------------------------------------------------------------------
// k3_sm: softmax (from raw scores + isp/osp biases) + sbar -> sOut, then
// 256-thread p-weighted reduction of XC (2-way row split) + LN ->
// outArr cell (f32) + compact split f16 at row g.
__global__ __launch_bounds__(256) void k3_sm(
    const float* __restrict__ XC, const float* __restrict__ scores,
    const float* __restrict__ isp, float* __restrict__ sOut,
    const float* __restrict__ lng, const float* __restrict__ lnb,
    float* __restrict__ outArr, h16* __restrict__ outh, h16* __restrict__ outl,
    int lvl, int np, int Ls, int offL, int inside, int doSM) {
  int g = blockIdx.x;
  int b = g / Ls, pos = g - b * Ls;
  int tid = threadIdx.x, lane = tid & 63, wv = tid >> 6;
  __shared__ float pb[32];
  __shared__ float comb[384];
  __shared__ float r1[2], r2[2];
  size_t cb = (size_t)b * NCELLS;

  if (doSM) {
    if (wv == 0) {
      float sc = -3.0e38f;
      if (lane < np) {
        float biasv;
        if (inside) {
          int lc = offf(lane) + pos;
          int rc = offf(np - 1 - lane) + pos + lane + 1;
          biasv = isp[cb + lc] + isp[cb + rc];
        } else {
          int par, sib;
          int cnt0 = 31 - pos - lvl;
          if (lane < cnt0) { par = offf(lvl + lane + 1) + pos; sib = offf(lane) + pos + lvl + 1; }
          else { int s2 = lane - cnt0; par = offf(lvl + s2 + 1) + pos - s2 - 1; sib = offf(s2) + pos - s2 - 1; }
          biasv = isp[cb + sib] + sOut[cb + par];
        }
        sc = scores[(size_t)g * np + lane] + biasv;
      }
      float m = sc;
#pragma unroll
      for (int o = 32; o; o >>= 1) m = fmaxf(m, __shfl_xor(m, o, 64));
      float e = (lane < np) ? __expf(sc - m) : 0.0f;
      float S = e;
#pragma unroll
      for (int o = 32; o; o >>= 1) S += __shfl_xor(S, o, 64);
      float pn = e / S;
      if (lane < np) pb[lane] = pn;
      float sb = (lane < np) ? pn * sc : 0.0f;
#pragma unroll
      for (int o = 32; o; o >>= 1) sb += __shfl_xor(sb, o, 64);
      if (lane == 0) sOut[cb + offL + pos] = sb;
    }
  } else {
    if (tid == 0) pb[0] = 1.0f;
  }
  __syncthreads();

  int gi = tid >> 7, t2 = tid & 127;
  float a0 = 0.f, a1 = 0.f, a2 = 0.f;
  const float* base = XC + (size_t)g * np * DD;
  for (int n = gi; n < np; n += 2) {
    float pw = pb[n];
    const float* row = base + (size_t)n * DD;
    a0 += pw * row[t2];
    a1 += pw * row[t2 + 128];
    a2 += pw * row[t2 + 256];
  }
  if (gi == 1) { comb[t2] = a0; comb[t2 + 128] = a1; comb[t2 + 256] = a2; }
  __syncthreads();
  if (gi == 0) { a0 += comb[t2]; a1 += comb[t2 + 128]; a2 += comb[t2 + 256]; }
  float s = a0 + a1 + a2;
#pragma unroll
  for (int o = 32; o; o >>= 1) s += __shfl_xor(s, o, 64);
  if (gi == 0 && lane == 0) r1[wv] = s;
  __syncthreads();
  float mean = (r1[0] + r1[1]) * (1.0f / 384.0f);
  float d0 = a0 - mean, d1 = a1 - mean, d2 = a2 - mean;
  float q = d0 * d0 + d1 * d1 + d2 * d2;
#pragma unroll
  for (int o = 32; o; o >>= 1) q += __shfl_xor(q, o, 64);
  if (gi == 0 && lane == 0) r2[wv] = q;
  __syncthreads();
  if (gi == 0) {
    float var = (r2[0] + r2[1]) * (1.0f / 384.0f);
    float inv = rsqrtf(var + 1e-5f);
    size_t ob = ((size_t)b * NCELLS + offL + pos) * DD;
    float* out = outArr + ob;
    float v0 = d0 * inv * lng[t2]       + lnb[t2];
    float v1 = d1 * inv * lng[t2 + 128] + lnb[t2 + 128];
    float v2 = d2 * inv * lng[t2 + 256] + lnb[t2 + 256];
    out[t2]       = v0;
    out[t2 + 128] = v1;
    out[t2 + 256] = v2;
    size_t sb = (size_t)g * DD;
    h16 h;
    h = (h16)v0; outh[sb + t2]       = h; outl[sb + t2]       = (h16)(v0 - (float)h);
    h = (h16)v1; outh[sb + t2 + 128] = h; outl[sb + t2 + 128] = (h16)(v1 - (float)h);
    h = (h16)v2; outh[sb + t2 + 256] = h; outl[sb + t2 + 256] = (h16)(v2 - (float)h);
  }
}

// ---------------------------------------------------------------------------
// Root: oh[b][527] = LN(root_h), P0[b][527] = LN(root_h) @ out_W0.
__global__ __launch_bounds__(384) void root_k(
    const float* __restrict__ rooth, const float* __restrict__ lng,
    const float* __restrict__ lnb, const float* __restrict__ W0,
    float* __restrict__ ohp, float* __restrict__ P0) {
  int tid = threadIdx.x;
  int lane = tid & 63, wv = tid >> 6;
  __shared__ float rl[384];
  __shared__ float r1[6], r2[6];
  float x = rooth[tid];
  float s = x;
#pragma unroll
  for (int o = 32; o; o >>= 1) s += __shfl_xor(s, o, 64);
  if (lane == 0) r1[wv] = s;
  __syncthreads();
  float mean = (r1[0] + r1[1] + r1[2] + r1[3] + r1[4] + r1[5]) * (1.0f / 384.0f);
  float d = x - mean;
  float q = d * d;
#pragma unroll
  for (int o = 32; o; o >>= 1) q += __shfl_xor(q, o, 64);
  if (lane == 0) r2[wv] = q;
  __syncthreads();
  float var = (r2[0] + r2[1] + r2[2] + r2[3] + r2[4] + r2[5]) * (1.0f / 384.0f);
  float inv = rsqrtf(var + 1e-5f);
  float v = d * inv * lng[tid] + lnb[tid];
  rl[tid] = v;
  __syncthreads();
  for (int b2 = 0; b2 < BDIM; ++b2)
    ohp[((size_t)b2 * NCELLS + 527) * DD + tid] = v;
  float acc = 0.0f;
  for (int d2 = 0; d2 < 384; ++d2) acc += rl[d2] * W0[(size_t)d2 * 384 + tid];
  for (int b2 = 0; b2 < BDIM; ++b2)
    P0[((size_t)b2 * NCELLS + 527) * DD + tid] = acc;
}

// ---------------------------------------------------------------------------
extern "C" void kernel_launch(void* const* d_in, const int* in_sizes, int n_in,
                              void* d_out, int out_size, void* d_ws, size_t ws_size,
                              hipStream_t stream) {
  const float* x        = (const float*)d_in[0];
  const float* leaf_W   = (const float*)d_in[1];
  const float* leaf_b   = (const float*)d_in[2];
  const float* in_ln_g  = (const float*)d_in[3];
  const float* in_ln_b  = (const float*)d_in[4];
  const float* out_ln_g = (const float*)d_in[5];
  const float* out_ln_b = (const float*)d_in[6];
  const float* root_h   = (const float*)d_in[7];
  const float* in_bi    = (const float*)d_in[8];
  const float* out_bi   = (const float*)d_in[9];
  const float* in_W0    = (const float*)d_in[10];
  const float* in_W1    = (const float*)d_in[11];
  const float* in_B0    = (const float*)d_in[12];
  const float* in_W2    = (const float*)d_in[13];
  const float* in_B1    = (const float*)d_in[14];
  const float* out_W0   = (const float*)d_in[15];
  const float* out_W1   = (const float*)d_in[16];
  const float* out_B0   = (const float*)d_in[17];
  const float* out_W2   = (const float*)d_in[18];
  const float* out_B1   = (const float*)d_in[19];

  float* ih  = (float*)d_out;
  float* isp = ih + (size_t)BDIM * NCELLS * DD;
  float* oh  = isp + (size_t)BDIM * NCELLS;
  float* osp = oh + (size_t)BDIM * NCELLS * DD;

  // workspace layout — identical footprint to the round-2/8/10 kernels.
  float* PC  = (float*)d_ws;                                // 32,440,320 f
  float* P0  = PC + (size_t)32440320;                       //  6,488,064 f
  float* XCb = P0 + (size_t)6488064;                        // 12,189,696 f
  float* Pw  = XCb + (size_t)12189696;                      //     31,744 f (raw scores)
  h16* Hh    = (h16*)(Pw + 31744);                          // 12,189,696 h
  h16* Hl    = Hh + (size_t)12189696;                       // 12,189,696 h
  h16* WCth  = Hl + (size_t)12189696;                       //    737,280 h
  h16* WCtl  = WCth + (size_t)737280;
  h16* W2th  = WCtl + (size_t)737280;                       //    147,456 h each
  h16* W2tl  = W2th + (size_t)147456;
  h16* OW2th = W2tl + (size_t)147456;
  h16* OW2tl = OW2th + (size_t)147456;
  h16* OW0th = OW2tl + (size_t)147456;
  h16* OW0tl = OW0th + (size_t)147456;
  h16* LWth  = OW0tl + (size_t)147456;
  h16* LWtl  = LWth + (size_t)147456;
  // aliases inside the H buffer:
  h16* xh = Hh;                          // rows 0..1023: split x (leaf only)
  h16* xl = Hl;
  h16* Ch = Hh + (size_t)16384 * DD;     // compact split of current level
  h16* Cl = Hl + (size_t)16384 * DD;

  pack3_k<<<2880, 256, 0, stream>>>(in_W0, in_W1, in_bi, out_W1, out_bi,
                                    in_W2, out_W2, out_W0, leaf_W, x,
                                    WCth, WCtl, W2th, W2tl, OW2th, OW2tl,
                                    OW0th, OW0tl, LWth, LWtl, xh, xl,
                                    isp, osp);

  // leaf: T = sigma_h(x @ leaf_W + b); ih[level0] = LN(T); PC for leaves
  gemmh<<<dim3(16, 3), 256, 0, stream>>>(xh, xl, LWth, LWtl, leaf_b, XCb, 1024, 384, 1, 0, 0);
  k3_sm<<<1024, 256, 0, stream>>>(XCb, Pw, isp, isp, in_ln_g, in_ln_b,
                                  ih, Ch, Cl, 0, 1, 32, 0, 1, 0);
  gemmh<<<dim3(16, 15), 256, 0, stream>>>(Ch, Cl, WCth, WCtl, nullptr, PC, 1024, 1920, 0, 32, 0);

  // inside pass
  for (int L = 1; L < LEN; ++L) {
    int Ls = LEN - L, G = BDIM * Ls, M = G * L, off = offh(L);
    k1s<<<dim3(G, (L + 3) / 4), 256, 0, stream>>>(PC, nullptr, ih, Pw, Hh, Hl,
                                                  in_B0, L, L, Ls, 1);
    gemmh<<<dim3((M + 63) / 64, 3), 256, 0, stream>>>(Hh, Hl, W2th, W2tl, in_B1, XCb, M, 384, 1, 0, 0);
    k3_sm<<<G, 256, 0, stream>>>(XCb, Pw, isp, isp, in_ln_g, in_ln_b,
                                 ih, Ch, Cl, L, L, Ls, off, 1, 1);
    gemmh<<<dim3((G + 63) / 64, 15), 256, 0, stream>>>(Ch, Cl, WCth, WCtl, nullptr, PC, G, 1920, 0, Ls, off);
  }

  // root
  root_k<<<1, 384, 0, stream>>>(root_h, out_ln_g, out_ln_b, out_W0, oh, P0);

  // outside pass
  for (int L = LEN - 2; L >= 0; --L) {
    int Ls = LEN - L, G = BDIM * Ls, Nc = LEN - 1 - L, M = G * Nc, off = offh(L);
    k1s<<<dim3(G, (Nc + 3) / 4), 256, 0, stream>>>(PC, P0, oh, Pw, Hh, Hl,
                                                   out_B0, L, Nc, Ls, 0);
    gemmh<<<dim3((M + 63) / 64, 3), 256, 0, stream>>>(Hh, Hl, OW2th, OW2tl, out_B1, XCb, M, 384, 1, 0, 0);
    k3_sm<<<G, 256, 0, stream>>>(XCb, Pw, isp, osp, out_ln_g, out_ln_b,
                                 oh, Ch, Cl, L, Nc, Ls, off, 0, 1);
    gemmh<<<dim3((G + 63) / 64, 3), 256, 0, stream>>>(Ch, Cl, OW0th, OW0tl, nullptr, P0, G, 384, 0, Ls, off);
  }
}